// Round 12
// baseline (171.766 us; speedup 1.0000x reference)
//
#include <hip/hip_runtime.h>

// CRF loss, B=1024, T=512, K=32 — BATCHED-MATVEC serial scan (reformulation).
//
// r4-r11 ledger: the chunked-matmat scan is pinned at ~62-81 µs across eight
// structural variants (chains/SIMD {4,8,16}, VALU cuts, LDS-free) — 512
// matmat steps/SIMD x ~290cy is the formulation's floor. Root cause: chunking
// pays a 32x FLOP + 4x VALU blowup (full 32x32 transfer-matrix products) to
// parallelize T. But B=1024 sequences already provide the parallelism:
//
// crf_scan: 64 WGs x 1 wave; wave owns 16 SEQUENCES (MFMA N-dim), T serial.
//   alpha' = D_t (A_hat alpha), A_hat[i,k] = exp(trans[k,i])/32 (constant):
//   * per step: 2x mfma_16x16x32_bf16 (tags lo/hi) + 8 exp + 8 mul + 4 pack.
//     64x less MFMA work, 4x less exp/scale/pack than the chunked form.
//   * same pi-permuted k-order as the proven kernels: V slot (g,e) <-> tag
//     (e<4 ? 4g+e : 16+4g+(e-4)); lane's C rows ARE its next V slots; the
//     emit float4 pair (tags 4g.., 16+4g..) matches elem order exactly.
//   * fragment roles: V col = lane&15 = seq; C col = seq, row = 4g+reg (lo)
//     / 16+4g+reg (hi) — mappings identical to the r8-verified kernel.
//   * emits prefetched in 8-step register groups, double-buffered (A/B);
//     1 wave/SIMD -> ~180 VGPR is free; loads for group k+2 issue while
//     group k+1 processes (~450cy cover for HBM latency).
//   * per-SEQ renorm every 8 steps: ref = scaled c_lo[0] of the seq's g=0
//     lane (shfl by n), exact pow2 exponent strip, eSum per lane.
//   * mask: whole-block all-ones precheck -> branch-free fast loop
//     (benchmark data is all-ones); general 0/1 masks take a per-step
//     cndmask slow path (per-lane select; renorm e forced 0 when masked).
//   * t=0 is the init (V = exp(emit0)); steps t=1..511.
//   * finale: sum tags (8 bf2f + shfl_xor 16/32), out = log(sum) +
//     eSum*ln2 + applied*ln32 - score.
// crf_score: 1024 WGs x 64 (massively parallel path/trans score gather),
//   launched FIRST; crf_scan reads wsScore (stream-ordered).

#define K32 32
#define Tt  512
#define SB  16

typedef float  float4v __attribute__((ext_vector_type(4)));
typedef short  short8v __attribute__((ext_vector_type(8)));

__device__ inline float bf2f_lo(unsigned d) { return __uint_as_float(d << 16); }
__device__ inline float bf2f_hi(unsigned d) { return __uint_as_float(d & 0xFFFF0000u); }

// pack two f32 -> bf16x2 dword by truncation: low16 = hi16(lo), high16 = hi16(hi)
__device__ inline unsigned pack_trunc(float hi, float lo) {
    return __builtin_amdgcn_perm(__float_as_uint(hi), __float_as_uint(lo), 0x07060302u);
}
// round-to-nearest-even bf16 (one-time constants only)
__device__ inline unsigned short f2bf_rne(float x) {
    unsigned u = __float_as_uint(x);
    return (unsigned short)((u + 0x7FFFu + ((u >> 16) & 1u)) >> 16);
}

union F8 { unsigned u[4]; short8v v; };

// ---------------- path/transition score (massively parallel gather) ----------------
__global__ __launch_bounds__(64) void crf_score(
    const int*   __restrict__ labels,
    const float* __restrict__ y_pred,
    const float* __restrict__ trans,
    const float* __restrict__ mask,
    float*       __restrict__ wsScore)
{
    const int s    = blockIdx.x;
    const int lane = threadIdx.x;
    const int*   lb  = labels + (size_t)s * Tt;
    const float* mkp = mask   + (size_t)s * Tt;
    const float* yp  = y_pred + (size_t)s * Tt * K32;

    float sc = 0.0f;
#pragma unroll
    for (int j = 0; j < 8; ++j) {
        const int t   = j * 64 + lane;
        const int lab = lb[t];
        const float m = mkp[t];
        sc += yp[t * K32 + lab] * m;
        if (t < Tt - 1) sc += trans[lab * K32 + lb[t + 1]] * (m * mkp[t + 1]);
    }
#pragma unroll
    for (int sft = 1; sft < 64; sft <<= 1) sc += __shfl_xor(sc, sft, 64);
    if (lane == 0) wsScore[s] = sc;
}

// ---------------- batched-matvec serial scan ----------------
__global__ __launch_bounds__(64) void crf_scan(
    const float* __restrict__ y_pred,
    const float* __restrict__ trans,
    const float* __restrict__ mask,
    const float* __restrict__ wsScore,
    float*       __restrict__ out)
{
    const int lane = threadIdx.x;
    const int n    = lane & 15;               // sequence slot (MFMA column)
    const int g    = lane >> 4;               // k-group / row-group
    const int sb   = blockIdx.x * SB;

    const float* yp_n = y_pred + (size_t)(sb + n) * Tt * K32;
    const float* mk_n = mask   + (size_t)(sb + n) * Tt;

    // ---- A_hat = exp(trans^T)/32, bf16, pi-k-order; rows n (lo) / 16+n (hi) ----
    F8 Alo, Ahi;
#pragma unroll
    for (int h = 0; h < 4; ++h) {
        const int k0 = (h < 2) ? (g * 4 + 2 * h) : (16 + g * 4 + 2 * (h - 2));
        const int k1 = k0 + 1;
        Alo.u[h] = ((unsigned)f2bf_rne(__expf(trans[k0 * K32 + n]) * 0.03125f)) |
                   (((unsigned)f2bf_rne(__expf(trans[k1 * K32 + n]) * 0.03125f)) << 16);
        Ahi.u[h] = ((unsigned)f2bf_rne(__expf(trans[k0 * K32 + 16 + n]) * 0.03125f)) |
                   (((unsigned)f2bf_rne(__expf(trans[k1 * K32 + 16 + n]) * 0.03125f)) << 16);
    }

    // ---- whole-block mask precheck (16 seqs x 512 steps; quartered over g) ----
    bool allones;
    {
        float mn = 1.0f;
        const float4* m4 = (const float4*)(mk_n + g * 128);
#pragma unroll
        for (int j = 0; j < 32; ++j) {
            const float4 v = m4[j];
            mn = fminf(mn, fminf(fminf(v.x, v.y), fminf(v.z, v.w)));
        }
        allones = (__ballot(mn == 1.0f) == ~0ull);
    }

    const float4v zf = {0.f, 0.f, 0.f, 0.f};
    F8 V;
    int eSum    = 0;
    int applied = 0;

    float4 bufA[16], bufB[16];                // 8-step emit groups (double buffer)

    auto LOADG = [&](float4 (&buf)[16], int grp) {
#pragma unroll
        for (int i = 0; i < 8; ++i) {
            const int t = grp * 8 + i;
            buf[2 * i]     = *(const float4*)(yp_n + t * K32 + 4 * g);
            buf[2 * i + 1] = *(const float4*)(yp_n + t * K32 + 16 + 4 * g);
        }
    };

    LOADG(bufA, 0);
    {   // init: V = exp(emit[t=0])  (alpha0; t=0 is not a scan step)
        const float4 lo = bufA[0], hi = bufA[1];
        V.u[0] = pack_trunc(__expf(lo.y), __expf(lo.x));
        V.u[1] = pack_trunc(__expf(lo.w), __expf(lo.z));
        V.u[2] = pack_trunc(__expf(hi.y), __expf(hi.x));
        V.u[3] = pack_trunc(__expf(hi.w), __expf(hi.z));
    }
    LOADG(bufB, 1);

    // one scan step (fast path, no mask)
    auto stepf = [&](const float4 lo, const float4 hi, bool ren) {
        float4v cl = __builtin_amdgcn_mfma_f32_16x16x32_bf16(Alo.v, V.v, zf, 0, 0, 0);
        float4v ch = __builtin_amdgcn_mfma_f32_16x16x32_bf16(Ahi.v, V.v, zf, 0, 0, 0);
        const float4v d0 = {__expf(lo.x), __expf(lo.y), __expf(lo.z), __expf(lo.w)};
        const float4v d1 = {__expf(hi.x), __expf(hi.y), __expf(hi.z), __expf(hi.w)};
        cl *= d0; ch *= d1;
        if (ren) {                            // exact per-seq pow2 renorm
            const float rb = __shfl(cl[0], n, 64);
            const int e = (int)((__float_as_uint(rb) >> 23) & 255u) - 127;
            const float rs = __uint_as_float((unsigned)(127 - e) << 23);
            cl *= rs; ch *= rs;
            eSum += e;
        }
        V.u[0] = pack_trunc(cl[1], cl[0]);
        V.u[1] = pack_trunc(cl[3], cl[2]);
        V.u[2] = pack_trunc(ch[1], ch[0]);
        V.u[3] = pack_trunc(ch[3], ch[2]);
    };

    // one scan step (slow path, per-lane 0/1 mask)
    auto stepm = [&](const float4 lo, const float4 hi, int t, bool ren) {
        const float m  = mk_n[t];
        const bool vm  = (m != 0.0f);
        float4v cl = __builtin_amdgcn_mfma_f32_16x16x32_bf16(Alo.v, V.v, zf, 0, 0, 0);
        float4v ch = __builtin_amdgcn_mfma_f32_16x16x32_bf16(Ahi.v, V.v, zf, 0, 0, 0);
        const float4v d0 = {__expf(lo.x), __expf(lo.y), __expf(lo.z), __expf(lo.w)};
        const float4v d1 = {__expf(hi.x), __expf(hi.y), __expf(hi.z), __expf(hi.w)};
        cl *= d0; ch *= d1;
        if (ren) {
            const float rb = __shfl(cl[0], n, 64);
            int e = (int)((__float_as_uint(rb) >> 23) & 255u) - 127;
            e = vm ? e : 0;                   // masked seq: no renorm this cycle
            const float rs = __uint_as_float((unsigned)(127 - e) << 23);
            cl *= rs; ch *= rs;
            eSum += e;
        }
        const unsigned v0 = pack_trunc(cl[1], cl[0]);
        const unsigned v1 = pack_trunc(cl[3], cl[2]);
        const unsigned v2 = pack_trunc(ch[1], ch[0]);
        const unsigned v3 = pack_trunc(ch[3], ch[2]);
        V.u[0] = vm ? v0 : V.u[0];
        V.u[1] = vm ? v1 : V.u[1];
        V.u[2] = vm ? v2 : V.u[2];
        V.u[3] = vm ? v3 : V.u[3];
        applied += vm ? 1 : 0;
    };

    if (allones) {
        applied = Tt - 1;
        for (int bb = 0; bb < 32; ++bb) {     // rolled: 2 groups (16 steps) per iter
            if (bb > 0) stepf(bufA[0], bufA[1], false);   // t=0 skipped in group 0
            stepf(bufA[2],  bufA[3],  false);
            stepf(bufA[4],  bufA[5],  false);
            stepf(bufA[6],  bufA[7],  false);
            stepf(bufA[8],  bufA[9],  false);
            stepf(bufA[10], bufA[11], false);
            stepf(bufA[12], bufA[13], false);
            stepf(bufA[14], bufA[15], true);
            if (bb < 31) LOADG(bufA, 2 * bb + 2);
            stepf(bufB[0],  bufB[1],  false);
            stepf(bufB[2],  bufB[3],  false);
            stepf(bufB[4],  bufB[5],  false);
            stepf(bufB[6],  bufB[7],  false);
            stepf(bufB[8],  bufB[9],  false);
            stepf(bufB[10], bufB[11], false);
            stepf(bufB[12], bufB[13], false);
            stepf(bufB[14], bufB[15], true);
            if (bb < 31) LOADG(bufB, 2 * bb + 3);
        }
    } else {
        for (int bb = 0; bb < 32; ++bb) {
            const int tA = bb * 16, tB = tA + 8;
            if (bb > 0) stepm(bufA[0], bufA[1], tA + 0, false);
            stepm(bufA[2],  bufA[3],  tA + 1, false);
            stepm(bufA[4],  bufA[5],  tA + 2, false);
            stepm(bufA[6],  bufA[7],  tA + 3, false);
            stepm(bufA[8],  bufA[9],  tA + 4, false);
            stepm(bufA[10], bufA[11], tA + 5, false);
            stepm(bufA[12], bufA[13], tA + 6, false);
            stepm(bufA[14], bufA[15], tA + 7, true);
            if (bb < 31) LOADG(bufA, 2 * bb + 2);
            stepm(bufB[0],  bufB[1],  tB + 0, false);
            stepm(bufB[2],  bufB[3],  tB + 1, false);
            stepm(bufB[4],  bufB[5],  tB + 2, false);
            stepm(bufB[6],  bufB[7],  tB + 3, false);
            stepm(bufB[8],  bufB[9],  tB + 4, false);
            stepm(bufB[10], bufB[11], tB + 5, false);
            stepm(bufB[12], bufB[13], tB + 6, false);
            stepm(bufB[14], bufB[15], tB + 7, true);
            if (bb < 31) LOADG(bufB, 2 * bb + 3);
        }
    }

    // ---- finale: per-seq logsumexp of alpha_T ----
    float ssum = bf2f_lo(V.u[0]) + bf2f_hi(V.u[0]) +
                 bf2f_lo(V.u[1]) + bf2f_hi(V.u[1]) +
                 bf2f_lo(V.u[2]) + bf2f_hi(V.u[2]) +
                 bf2f_lo(V.u[3]) + bf2f_hi(V.u[3]);
    ssum += __shfl_xor(ssum, 16, 64);
    ssum += __shfl_xor(ssum, 32, 64);

    if (lane < 16) {
        out[sb + n] = __logf(ssum) + (float)eSum * 0.693147180559945f +
                      (float)applied * 3.46573590f - wsScore[sb + n];
    }
}

extern "C" void kernel_launch(void* const* d_in, const int* in_sizes, int n_in,
                              void* d_out, int out_size, void* d_ws, size_t ws_size,
                              hipStream_t stream) {
    const int*   labels = (const int*)  d_in[0];
    const float* y_pred = (const float*)d_in[1];
    const float* trans  = (const float*)d_in[2];
    const float* mask   = (const float*)d_in[3];
    float* out = (float*)d_out;
    float* wsScore = (float*)d_ws;

    crf_score<<<1024, 64, 0, stream>>>(labels, y_pred, trans, mask, wsScore);
    crf_scan<<<64, 64, 0, stream>>>(y_pred, trans, mask, wsScore, out);
}